// Round 7
// baseline (903.384 us; speedup 1.0000x reference)
//
#include <hip/hip_runtime.h>
#include <hip/hip_bf16.h>
#include <stdint.h>

#define M_TOT 8192
#define N_TOT 16384
#define K_TOT 4096

typedef int v4i __attribute__((ext_vector_type(4)));
typedef int v16i __attribute__((ext_vector_type(16)));

__device__ __forceinline__ float fix_scale(float s) { return s == 0.0f ? 1.0f : s; }

__device__ __forceinline__ void gload_lds16(const void* g, void* l) {
    __builtin_amdgcn_global_load_lds((__attribute__((address_space(1))) void*)g,
                                     (__attribute__((address_space(3))) void*)l,
                                     16, 0, 0);
}

// LDS swizzle for [row][64B] tiles: XOR 16B-granule bits (4..5) with row bits 1..2
// (byte bits 7..8). Involution; verified conflict-free (round 2: 6.7e7 -> 0).
// NOTE (round-6 lesson): swz is NOT additive — every read offset must be computed
// through swz, never as swz(base)+delta.
__device__ __forceinline__ int swz(int byte_off) {
    return byte_off ^ (((byte_off >> 7) & 3) << 4);
}

__device__ __forceinline__ int8_t quant1(float x, float scale) {
    float r = fminf(127.0f, fmaxf(-127.0f, rintf(x / scale)));
    return (int8_t)(int)r;
}

// ---------------- lhs: per-row absmax quantize ----------------
__global__ __launch_bounds__(256) void k_quant_lhs(const float* __restrict__ x,
                                                   int8_t* __restrict__ q,
                                                   float* __restrict__ s) {
    const int row = blockIdx.x;
    const int t = threadIdx.x;
    const float* xr = x + (size_t)row * K_TOT;
    float4 v[4];
    float m = 0.0f;
#pragma unroll
    for (int i = 0; i < 4; ++i) {
        v[i] = ((const float4*)xr)[i * 256 + t];
        m = fmaxf(m, fmaxf(fmaxf(fabsf(v[i].x), fabsf(v[i].y)),
                           fmaxf(fabsf(v[i].z), fabsf(v[i].w))));
    }
#pragma unroll
    for (int off = 32; off; off >>= 1) m = fmaxf(m, __shfl_xor(m, off));
    __shared__ float wmax[4];
    if ((t & 63) == 0) wmax[t >> 6] = m;
    __syncthreads();
    m = fmaxf(fmaxf(wmax[0], wmax[1]), fmaxf(wmax[2], wmax[3]));
    const float scale = fix_scale(m / 127.0f);
    if (t == 0) s[row] = scale;
    unsigned* qrow = (unsigned*)(q + (size_t)row * K_TOT);
#pragma unroll
    for (int i = 0; i < 4; ++i) {
        unsigned b0 = (unsigned char)quant1(v[i].x, scale);
        unsigned b1 = (unsigned char)quant1(v[i].y, scale);
        unsigned b2 = (unsigned char)quant1(v[i].z, scale);
        unsigned b3 = (unsigned char)quant1(v[i].w, scale);
        qrow[i * 256 + t] = b0 | (b1 << 8) | (b2 << 16) | (b3 << 24);
    }
}

// ---------------- rhs: per-column absmax (atomicMax on float bits) ----------------
__global__ __launch_bounds__(256) void k_rhs_absmax(const float* __restrict__ rhs,
                                                    unsigned* __restrict__ amax) {
    const int f = blockIdx.x * 256 + threadIdx.x;
    const int d0 = blockIdx.y * 256;
    const float* p = rhs + (size_t)d0 * N_TOT + f;
    float m = 0.0f;
#pragma unroll 4
    for (int d = 0; d < 256; ++d)
        m = fmaxf(m, fabsf(p[(size_t)d * N_TOT]));
    atomicMax(amax + f, __float_as_uint(m));
}

__global__ __launch_bounds__(256) void k_rhs_scale(const unsigned* __restrict__ amax,
                                                   float* __restrict__ s) {
    const int f = blockIdx.x * 256 + threadIdx.x;
    s[f] = fix_scale(__uint_as_float(amax[f]) / 127.0f);
}

// ---------------- rhs: quantize + transpose to [N][K] ----------------
__global__ __launch_bounds__(256) void k_quant_rhs_t(const float* __restrict__ rhs,
                                                     const float* __restrict__ s,
                                                     int8_t* __restrict__ qT) {
    const int f0 = blockIdx.x * 64;
    const int d0 = blockIdx.y * 64;
    const int t = threadIdx.x;
    __shared__ float sc[64];
    __shared__ alignas(16) int8_t tile[64][64];  // [f local][d local]
    if (t < 64) sc[t] = s[f0 + t];
    __syncthreads();
    const int fl = (t & 15) * 4;
    const int rl = t >> 4;
#pragma unroll
    for (int i = 0; i < 4; ++i) {
        const int dl = i * 16 + rl;
        float4 v = *(const float4*)(rhs + (size_t)(d0 + dl) * N_TOT + f0 + fl);
        tile[fl + 0][dl] = quant1(v.x, sc[fl + 0]);
        tile[fl + 1][dl] = quant1(v.y, sc[fl + 1]);
        tile[fl + 2][dl] = quant1(v.z, sc[fl + 2]);
        tile[fl + 3][dl] = quant1(v.w, sc[fl + 3]);
    }
    __syncthreads();
    const int fr = t >> 2;
    const int dc = (t & 3) * 16;
    *(int4*)(qT + (size_t)(f0 + fr) * K_TOT + d0 + dc) = *(const int4*)&tile[fr][dc];
}

// ---- int8 GEMM: BM=256 BN=128, 4 waves of 128x64 (32x32x32 MFMA), 2 blocks/CU ----
#define BM 256
#define BN 128
#define BK 64
#define NKT (K_TOT / BK)   // 64

__global__ __launch_bounds__(256, 2) void k_gemm(const int8_t* __restrict__ qA,   // [M][K]
                                                 const int8_t* __restrict__ qB,   // [N][K]
                                                 const float* __restrict__ sA,
                                                 const float* __restrict__ sB,
                                                 float* __restrict__ C) {
    __shared__ alignas(1024) int8_t As[3][BM * BK];   // 3 x 16 KB
    __shared__ alignas(1024) int8_t Bs[3][BN * BK];   // 3 x  8 KB  (72 KB -> 2 blocks/CU)

    // supercolumn raster: 4 bn-tiles wide (round-3/5 verified: FETCH ~420 MB)
    const int bid = blockIdx.x;          // 0..4095
    const int sc = bid >> 7;             // 32 supercolumns
    const int ii = bid & 127;
    const int bm0 = (ii & 31) << 8;                 // m-tile * 256
    const int bn0 = ((sc << 2) | (ii >> 5)) << 7;   // n-tile * 128

    const int tid = threadIdx.x;         // 0..255
    const int wave = tid >> 6;
    const int lane = tid & 63;
    const int wm = (wave >> 1) * 128;    // 2 wave-rows (128 rows each)
    const int wn = (wave & 1) * 64;      // 2 wave-cols (64 cols each)

    // staging: linear LDS dest + inverse-swizzled global source (rule #21)
    const int8_t* aSrc[4];
    const int8_t* bSrc[2];
#pragma unroll
    for (int i = 0; i < 4; ++i) {
        const int l = swz(i * 4096 + tid * 16);
        aSrc[i] = qA + (size_t)(bm0 + (l >> 6)) * K_TOT + (l & 63);
    }
#pragma unroll
    for (int i = 0; i < 2; ++i) {
        const int l = swz(i * 4096 + tid * 16);
        bSrc[i] = qB + (size_t)(bn0 + (l >> 6)) * K_TOT + (l & 63);
    }

    // swizzled fragment read offsets (32x32 frags: row = lane&31, k-byte = (lane>>5)*16).
    // ks=1 slice (k-bytes 32..63) computed THROUGH swz (round-6 fix: swz is not additive).
    int offA0[4], offA1[4], offB0[2], offB1[2];
#pragma unroll
    for (int f = 0; f < 4; ++f) {
        const int base = (wm + f * 32 + (lane & 31)) * BK + (lane >> 5) * 16;
        offA0[f] = swz(base);
        offA1[f] = swz(base + 32);
    }
#pragma unroll
    for (int n = 0; n < 2; ++n) {
        const int base = (wn + n * 32 + (lane & 31)) * BK + (lane >> 5) * 16;
        offB0[n] = swz(base);
        offB1[n] = swz(base + 32);
    }

    v16i acc[4][2];
#pragma unroll
    for (int f = 0; f < 4; ++f)
#pragma unroll
        for (int n = 0; n < 2; ++n)
#pragma unroll
            for (int e = 0; e < 16; ++e) acc[f][n][e] = 0;

    auto stage = [&](int kt) {
        const int b = kt % 3;
#pragma unroll
        for (int i = 0; i < 4; ++i)
            gload_lds16(aSrc[i] + kt * BK, &As[b][i * 4096 + tid * 16]);
#pragma unroll
        for (int i = 0; i < 2; ++i)
            gload_lds16(bSrc[i] + kt * BK, &Bs[b][i * 4096 + tid * 16]);
    };

    // prologue: stage kt=0,1 (12 loads out); wait kt0's 6 (keep kt1's in flight)
    stage(0);
    stage(1);
    asm volatile("s_waitcnt vmcnt(6)" ::: "memory");
    __builtin_amdgcn_s_barrier();

    for (int kt = 0; kt < NKT; ++kt) {
        if (kt + 2 < NKT) stage(kt + 2);

        const int8_t* a = As[kt % 3];
        const int8_t* b = Bs[kt % 3];
        v4i af0[4], af1[4], bf0[2], bf1[2];
#pragma unroll
        for (int f = 0; f < 4; ++f) {
            af0[f] = *(const v4i*)(a + offA0[f]);
            af1[f] = *(const v4i*)(a + offA1[f]);
        }
#pragma unroll
        for (int n = 0; n < 2; ++n) {
            bf0[n] = *(const v4i*)(b + offB0[n]);
            bf1[n] = *(const v4i*)(b + offB1[n]);
        }

        __builtin_amdgcn_s_setprio(1);
#pragma unroll
        for (int f = 0; f < 4; ++f)
#pragma unroll
            for (int n = 0; n < 2; ++n)
                acc[f][n] = __builtin_amdgcn_mfma_i32_32x32x32_i8(af0[f], bf0[n], acc[f][n], 0, 0, 0);
#pragma unroll
        for (int f = 0; f < 4; ++f)
#pragma unroll
            for (int n = 0; n < 2; ++n)
                acc[f][n] = __builtin_amdgcn_mfma_i32_32x32x32_i8(af1[f], bf1[n], acc[f][n], 0, 0, 0);
        __builtin_amdgcn_s_setprio(0);

        if (kt + 1 < NKT) {
            // counted vmcnt: keep kt+2's 6 loads in flight; drain only at the tail.
            if (kt + 2 < NKT) asm volatile("s_waitcnt vmcnt(6)" ::: "memory");
            else              asm volatile("s_waitcnt vmcnt(0)" ::: "memory");
            __builtin_amdgcn_s_barrier();
        }
    }

    // epilogue: dequant + store. 32x32 C/D: col = lane&31, row = (r&3)+8*(r>>2)+4*(lane>>5)
    const int cc0 = lane & 31;
    const int rbase = (lane >> 5) * 4;
#pragma unroll
    for (int f = 0; f < 4; ++f) {
#pragma unroll
        for (int r = 0; r < 16; ++r) {
            const int gr = bm0 + wm + f * 32 + (r & 3) + 8 * (r >> 2) + rbase;
            const float sa = sA[gr];
            float* crow = C + (size_t)gr * N_TOT + bn0 + wn;
#pragma unroll
            for (int n = 0; n < 2; ++n)
                crow[n * 32 + cc0] = (float)acc[f][n][r] * sa * sB[bn0 + wn + n * 32 + cc0];
        }
    }
}

extern "C" void kernel_launch(void* const* d_in, const int* in_sizes, int n_in,
                              void* d_out, int out_size, void* d_ws, size_t ws_size,
                              hipStream_t stream) {
    const float* lhs = (const float*)d_in[0];
    const float* rhs = (const float*)d_in[1];
    float* out = (float*)d_out;
    char* ws = (char*)d_ws;

    int8_t* qA = (int8_t*)ws;                                   // 32 MB
    int8_t* qB = (int8_t*)(ws + (size_t)33554432);              // 64 MB
    float* sA = (float*)(ws + (size_t)33554432 + 67108864);     // 32 KB
    float* sB = sA + M_TOT;                                     // 64 KB
    unsigned* amax = (unsigned*)(sB + N_TOT);                   // 64 KB

    hipMemsetAsync(amax, 0, N_TOT * sizeof(unsigned), stream);

    k_quant_lhs<<<M_TOT, 256, 0, stream>>>(lhs, qA, sA);
    k_rhs_absmax<<<dim3(N_TOT / 256, K_TOT / 256), 256, 0, stream>>>(rhs, amax);
    k_rhs_scale<<<N_TOT / 256, 256, 0, stream>>>(amax, sB);
    k_quant_rhs_t<<<dim3(N_TOT / 64, K_TOT / 64), 256, 0, stream>>>(rhs, sB, qB);
    k_gemm<<<(M_TOT / BM) * (N_TOT / BN), 256, 0, stream>>>(qA, qB, sA, sB, out);
}